// Round 3
// baseline (2013.743 us; speedup 1.0000x reference)
//
#include <hip/hip_runtime.h>
#include <hip/hip_fp16.h>

#define BLOCK 256
#define NB 4096        // target buckets
#define TILE 256       // max atoms per bucket (N <= NB*TILE for fast path)
#define GP 1024        // grid for hist/place kernels (multiple of BLOCK)

// ---------------- offsets scan (tiny) ----------------
__global__ void scan_offsets_kernel(const int* __restrict__ num_atoms, int B,
                                    int* __restrict__ offsets) {
    __shared__ long long partial[1024];
    int t = threadIdx.x;
    int per = (B + 1023) / 1024;
    int base_idx = t * per;
    long long local = 0;
    for (int i = 0; i < per; ++i) {
        int idx = base_idx + i;
        if (idx < B) local += num_atoms[idx];
    }
    partial[t] = local;
    __syncthreads();
    for (int d = 1; d < 1024; d <<= 1) {
        long long v = (t >= d) ? partial[t - d] : 0;
        __syncthreads();
        partial[t] += v;
        __syncthreads();
    }
    long long run = (t == 0) ? 0 : partial[t - 1];
    for (int i = 0; i < per; ++i) {
        int idx = base_idx + i;
        if (idx < B) {
            offsets[idx] = (int)run;
            run += num_atoms[idx];
        }
    }
    if (t == 1023) offsets[B] = (int)partial[1023];
}

__device__ __forceinline__ int find_batch(const int* __restrict__ offsets, int B, int n) {
    int lo = 0, hi = B;
    while (hi - lo > 1) {
        int mid = (lo + hi) >> 1;
        if (offsets[mid] <= n) lo = mid; else hi = mid;
    }
    return lo;
}

// ---------------- scaled = inv_lat^T f ; zero acc ----------------
__global__ void scale_kernel(const float* __restrict__ inv_lat,
                             const float* __restrict__ forces,
                             const int* __restrict__ offsets, int B, int N,
                             float* __restrict__ scaled, float* __restrict__ acc) {
    int n = blockIdx.x * blockDim.x + threadIdx.x;
    if (n >= N) return;
    int b = find_batch(offsets, B, n);
    const float* M = inv_lat + (size_t)b * 9;
    float f0 = forces[n * 3 + 0], f1 = forces[n * 3 + 1], f2 = forces[n * 3 + 2];
    float s0 = M[0] * f0 + M[3] * f1 + M[6] * f2;
    float s1 = M[1] * f0 + M[4] * f1 + M[7] * f2;
    float s2 = M[2] * f0 + M[5] * f1 + M[8] * f2;
    scaled[n * 3 + 0] = s0; scaled[n * 3 + 1] = s1; scaled[n * 3 + 2] = s2;
    acc[n * 3 + 0] = 0.f; acc[n * 3 + 1] = 0.f; acc[n * 3 + 2] = 0.f;
}

__device__ __forceinline__ int bucket_of(int tgt, int N) {
    return (int)(((unsigned long long)(unsigned)tgt * (unsigned)NB) / (unsigned)N);
}

// ---------------- pass 1: per-block bucket histogram (int4 loads) ----------------
__global__ __launch_bounds__(BLOCK) void hist_kernel(const int* __restrict__ symm_map,
                            long long chunk_base, int chunk_pairs, int N,
                            int* __restrict__ hist) {
    __shared__ int h[NB];
    int tid = threadIdx.x;
    for (int i = tid; i < NB; i += BLOCK) h[i] = 0;
    __syncthreads();
    int nblk = gridDim.x;
    int quantum = 4 * BLOCK;
    int span = ((chunk_pairs + (long long)nblk * quantum - 1) / ((long long)nblk * quantum)) * quantum;
    long long bs = (long long)blockIdx.x * span;
    int cnt = (int)((chunk_pairs - bs) < (long long)span ? (chunk_pairs - bs) : span);
    if (cnt > 0) {
        const int* p = symm_map + chunk_base + bs;
        int i0 = tid * 4;
        for (; i0 + 4 <= cnt; i0 += quantum) {
            int4 v = *(const int4*)(p + i0);
            atomicAdd(&h[bucket_of(v.x, N)], 1);
            atomicAdd(&h[bucket_of(v.y, N)], 1);
            atomicAdd(&h[bucket_of(v.z, N)], 1);
            atomicAdd(&h[bucket_of(v.w, N)], 1);
        }
        if (i0 < cnt) {  // at most one straddling quad per block
            for (int j = i0; j < cnt; ++j)
                atomicAdd(&h[bucket_of(p[j], N)], 1);
        }
    }
    __syncthreads();
    for (int i = tid; i < NB; i += BLOCK) hist[(size_t)blockIdx.x * NB + i] = h[i];
}

// ---------------- pass 2: per-bucket exclusive scan over GP blocks ----------------
__global__ __launch_bounds__(BLOCK) void scan_cols_kernel(const int* __restrict__ hist, int cap,
                                 int* __restrict__ offs, int* __restrict__ cnt) {
    const int K = GP / BLOCK;
    int b = blockIdx.x, tid = threadIdx.x;
    int v[K];
    int sum = 0;
    for (int k = 0; k < K; ++k) {
        v[k] = hist[(size_t)(tid * K + k) * NB + b];
        sum += v[k];
    }
    __shared__ int s[BLOCK];
    s[tid] = sum;
    __syncthreads();
    for (int d = 1; d < BLOCK; d <<= 1) {
        int x = (tid >= d) ? s[tid - d] : 0;
        __syncthreads();
        s[tid] += x;
        __syncthreads();
    }
    int run = b * cap + ((tid == 0) ? 0 : s[tid - 1]);
    for (int k = 0; k < K; ++k) {
        offs[(size_t)(tid * K + k) * NB + b] = run;
        run += v[k];
    }
    if (tid == BLOCK - 1) cnt[b] = (s[BLOCK - 1] < cap) ? s[BLOCK - 1] : cap;
}

// ---------------- pass 3: place 8B records grouped by bucket ----------------
// record = uint2 { h(v0) | h(v1)<<16 , h(v2) | (tgt&0xFFFF)<<16 }
__global__ __launch_bounds__(BLOCK) void place_kernel(const int* __restrict__ symm_map,
                             const float* __restrict__ scaled,
                             const float* __restrict__ general_ops,
                             const int* __restrict__ offs,
                             long long chunk_base, int chunk_pairs, int N, int O, int cap,
                             uint2* __restrict__ records, float* __restrict__ acc) {
    __shared__ int cur[NB];
    __shared__ float R[64 * 9];
    int tid = threadIdx.x;
    for (int i = tid; i < O * 9; i += BLOCK) {
        int o = i / 9, r = i - o * 9;
        R[i] = general_ops[o * 16 + (r / 3) * 4 + (r % 3)];
    }
    for (int i = tid; i < NB; i += BLOCK) cur[i] = offs[(size_t)blockIdx.x * NB + i];
    __syncthreads();
    int nblk = gridDim.x;
    int quantum = 4 * BLOCK;
    int span = ((chunk_pairs + (long long)nblk * quantum - 1) / ((long long)nblk * quantum)) * quantum;
    long long bs = (long long)blockIdx.x * span;
    int cnt = (int)((chunk_pairs - bs) < (long long)span ? (chunk_pairs - bs) : span);
    if (cnt <= 0) return;
    const int* p = symm_map + chunk_base + bs;
    unsigned tbase = (unsigned)(chunk_base + bs);
    unsigned uO = (unsigned)O;
    int i0 = tid * 4;
    unsigned t0 = tbase + (unsigned)i0;
    unsigned n = t0 / uO;
    unsigned o = t0 - n * uO;
    unsigned dq = (unsigned)quantum / uO;
    unsigned rq = (unsigned)quantum - dq * uO;
    for (; i0 + 4 <= cnt; i0 += quantum) {
        int4 tg = *(const int4*)(p + i0);
        unsigned nn = n, oo = o;
        #pragma unroll
        for (int j = 0; j < 4; ++j) {
            int tgt = (j == 0) ? tg.x : (j == 1) ? tg.y : (j == 2) ? tg.z : tg.w;
            const float* Ro = R + oo * 9;
            float s0 = scaled[nn * 3 + 0], s1 = scaled[nn * 3 + 1], s2 = scaled[nn * 3 + 2];
            float v0 = Ro[0] * s0 + Ro[1] * s1 + Ro[2] * s2;
            float v1 = Ro[3] * s0 + Ro[4] * s1 + Ro[5] * s2;
            float v2 = Ro[6] * s0 + Ro[7] * s1 + Ro[8] * s2;
            int bb = bucket_of(tgt, N);
            int pos = atomicAdd(&cur[bb], 1);
            if (pos - bb * cap < cap) {
                unsigned x = (unsigned)__half_as_ushort(__float2half_rn(v0)) |
                             ((unsigned)__half_as_ushort(__float2half_rn(v1)) << 16);
                unsigned y = (unsigned)__half_as_ushort(__float2half_rn(v2)) |
                             (((unsigned)tgt & 0xFFFFu) << 16);
                records[pos] = make_uint2(x, y);
            } else {
                atomicAdd(&acc[(size_t)tgt * 3 + 0], v0);
                atomicAdd(&acc[(size_t)tgt * 3 + 1], v1);
                atomicAdd(&acc[(size_t)tgt * 3 + 2], v2);
            }
            if (++oo == (unsigned)O) { oo = 0; ++nn; }
        }
        o += rq;
        if (o >= uO) { o -= uO; n += dq + 1; } else n += dq;
    }
    if (i0 < cnt) {  // straddling quad (at most 3 elements)
        unsigned nn = n, oo = o;
        for (int j = i0; j < cnt; ++j) {
            int tgt = p[j];
            const float* Ro = R + oo * 9;
            float s0 = scaled[nn * 3 + 0], s1 = scaled[nn * 3 + 1], s2 = scaled[nn * 3 + 2];
            float v0 = Ro[0] * s0 + Ro[1] * s1 + Ro[2] * s2;
            float v1 = Ro[3] * s0 + Ro[4] * s1 + Ro[5] * s2;
            float v2 = Ro[6] * s0 + Ro[7] * s1 + Ro[8] * s2;
            int bb = bucket_of(tgt, N);
            int pos = atomicAdd(&cur[bb], 1);
            if (pos - bb * cap < cap) {
                unsigned x = (unsigned)__half_as_ushort(__float2half_rn(v0)) |
                             ((unsigned)__half_as_ushort(__float2half_rn(v1)) << 16);
                unsigned y = (unsigned)__half_as_ushort(__float2half_rn(v2)) |
                             (((unsigned)tgt & 0xFFFFu) << 16);
                records[pos] = make_uint2(x, y);
            } else {
                atomicAdd(&acc[(size_t)tgt * 3 + 0], v0);
                atomicAdd(&acc[(size_t)tgt * 3 + 1], v1);
                atomicAdd(&acc[(size_t)tgt * 3 + 2], v2);
            }
            if (++oo == (unsigned)O) { oo = 0; ++nn; }
        }
    }
}

// ---------------- pass 4: per-bucket LDS accumulation ----------------
__global__ __launch_bounds__(BLOCK) void accum_kernel(const uint2* __restrict__ records,
                             const int* __restrict__ cnt, int N, int cap,
                             float* __restrict__ acc) {
    __shared__ float accL[TILE * 3];
    int b = blockIdx.x, tid = threadIdx.x;
    int lo = (int)(((long long)b * N + NB - 1) / NB);
    int hi = (int)(((long long)(b + 1) * N + NB - 1) / NB);
    if (hi > N) hi = N;
    int span3 = (hi - lo) * 3;
    for (int i = tid; i < span3; i += BLOCK) accL[i] = 0.f;
    __syncthreads();
    int c = cnt[b];
    const uint2* r = records + (size_t)b * cap;
    int lo16 = lo & 0xFFFF;
    int i = tid;
    for (; i + BLOCK < c; i += 2 * BLOCK) {
        uint2 f0 = r[i];
        uint2 f1 = r[i + BLOCK];
        {
            float v0 = __half2float(__ushort_as_half((unsigned short)(f0.x & 0xFFFF)));
            float v1 = __half2float(__ushort_as_half((unsigned short)(f0.x >> 16)));
            float v2 = __half2float(__ushort_as_half((unsigned short)(f0.y & 0xFFFF)));
            int local = ((int)(f0.y >> 16) - lo16) & 0xFFFF;
            atomicAdd(&accL[local * 3 + 0], v0);
            atomicAdd(&accL[local * 3 + 1], v1);
            atomicAdd(&accL[local * 3 + 2], v2);
        }
        {
            float v0 = __half2float(__ushort_as_half((unsigned short)(f1.x & 0xFFFF)));
            float v1 = __half2float(__ushort_as_half((unsigned short)(f1.x >> 16)));
            float v2 = __half2float(__ushort_as_half((unsigned short)(f1.y & 0xFFFF)));
            int local = ((int)(f1.y >> 16) - lo16) & 0xFFFF;
            atomicAdd(&accL[local * 3 + 0], v0);
            atomicAdd(&accL[local * 3 + 1], v1);
            atomicAdd(&accL[local * 3 + 2], v2);
        }
    }
    if (i < c) {
        uint2 f0 = r[i];
        float v0 = __half2float(__ushort_as_half((unsigned short)(f0.x & 0xFFFF)));
        float v1 = __half2float(__ushort_as_half((unsigned short)(f0.x >> 16)));
        float v2 = __half2float(__ushort_as_half((unsigned short)(f0.y & 0xFFFF)));
        int local = ((int)(f0.y >> 16) - lo16) & 0xFFFF;
        atomicAdd(&accL[local * 3 + 0], v0);
        atomicAdd(&accL[local * 3 + 1], v1);
        atomicAdd(&accL[local * 3 + 2], v2);
    }
    __syncthreads();
    float* g = acc + (size_t)lo * 3;
    for (int k = tid; k < span3; k += BLOCK) g[k] += accL[k];
}

// ---------------- fallback scatter (device atomics) ----------------
__global__ void scatter_kernel(const float* __restrict__ scaled,
                               const float* __restrict__ general_ops,
                               const int* __restrict__ symm_map,
                               float* __restrict__ acc,
                               long long total, int O) {
    __shared__ float rot_s[64 * 9];
    for (int i = threadIdx.x; i < O * 9; i += blockDim.x) {
        int o = i / 9, r = i - o * 9;
        rot_s[i] = general_ops[o * 16 + (r / 3) * 4 + (r % 3)];
    }
    __syncthreads();
    long long t = (long long)blockIdx.x * blockDim.x + threadIdx.x;
    if (t >= total) return;
    long long n = t / O;
    int o = (int)(t - n * O);
    float s0 = scaled[n * 3 + 0], s1 = scaled[n * 3 + 1], s2 = scaled[n * 3 + 2];
    const float* R = rot_s + o * 9;
    float v0 = R[0] * s0 + R[1] * s1 + R[2] * s2;
    float v1 = R[3] * s0 + R[4] * s1 + R[5] * s2;
    float v2 = R[6] * s0 + R[7] * s1 + R[8] * s2;
    int tgt = symm_map[t];
    atomicAdd(&acc[(size_t)tgt * 3 + 0], v0);
    atomicAdd(&acc[(size_t)tgt * 3 + 1], v1);
    atomicAdd(&acc[(size_t)tgt * 3 + 2], v2);
}

// ---------------- out = lat^T (acc / count) ----------------
__global__ void output_kernel(const float* __restrict__ lat,
                              const int* __restrict__ num_general_ops,
                              const int* __restrict__ offsets, int B, int N,
                              const float* __restrict__ acc,
                              float* __restrict__ out) {
    int n = blockIdx.x * blockDim.x + threadIdx.x;
    if (n >= N) return;
    int b = find_batch(offsets, B, n);
    float inv_cnt = 1.0f / (float)num_general_ops[b];
    float a0 = acc[n * 3 + 0] * inv_cnt;
    float a1 = acc[n * 3 + 1] * inv_cnt;
    float a2 = acc[n * 3 + 2] * inv_cnt;
    const float* M = lat + (size_t)b * 9;
    out[n * 3 + 0] = M[0] * a0 + M[3] * a1 + M[6] * a2;
    out[n * 3 + 1] = M[1] * a0 + M[4] * a1 + M[7] * a2;
    out[n * 3 + 2] = M[2] * a0 + M[5] * a1 + M[8] * a2;
}

static inline size_t align16(size_t x) { return (x + 15) & ~(size_t)15; }

extern "C" void kernel_launch(void* const* d_in, const int* in_sizes, int n_in,
                              void* d_out, int out_size, void* d_ws, size_t ws_size,
                              hipStream_t stream) {
    const float* lattices        = (const float*)d_in[0];
    const float* inv_lattices    = (const float*)d_in[1];
    const float* forces          = (const float*)d_in[2];
    const int*   num_atoms       = (const int*)d_in[3];
    const float* general_ops     = (const float*)d_in[4];
    const int*   symm_map        = (const int*)d_in[5];
    const int*   num_general_ops = (const int*)d_in[6];

    int B = in_sizes[0] / 9;
    int N = in_sizes[2] / 3;
    int O = in_sizes[4] / 16;
    long long total = (long long)N * O;

    // ---- workspace layout ----
    char* p = (char*)d_ws;
    size_t used = 0;
    float* scaled = (float*)(p + used); used = align16(used + (size_t)N * 3 * sizeof(float));
    float* acc    = (float*)(p + used); used = align16(used + (size_t)N * 3 * sizeof(float));
    int* offsets  = (int*)(p + used);   used = align16(used + (size_t)(B + 1) * sizeof(int));
    int* hist     = (int*)(p + used);   used = align16(used + (size_t)GP * NB * sizeof(int));
    int* offs     = (int*)(p + used);   used = align16(used + (size_t)GP * NB * sizeof(int));
    int* cnt      = (int*)(p + used);   used = align16(used + (size_t)NB * sizeof(int));
    size_t remaining = (ws_size > used) ? ws_size - used : 0;

    // choose chunk count C so 8B records fit; cap = mean + 25% + 512 slack
    const long long quantum = 4 * BLOCK;
    int C = -1, cap = 0;
    long long chunk_nom = 0;
    for (int c = 1; c <= 64; ++c) {
        long long cp = (total + c - 1) / c;
        cp = (cp + quantum - 1) / quantum * quantum;  // quad-aligned chunks
        long long mean = (cp + NB - 1) / NB;
        long long capc = mean + mean / 4 + 512;
        if ((size_t)NB * capc * sizeof(uint2) <= remaining) { C = c; cap = (int)capc; chunk_nom = cp; break; }
    }
    bool fast = (C > 0) && ((long long)N <= (long long)NB * TILE) && (O <= 64) && (total < (1LL << 31));

    int gridN = (N + BLOCK - 1) / BLOCK;
    scan_offsets_kernel<<<1, 1024, 0, stream>>>(num_atoms, B, offsets);

    if (fast) {
        uint2* records = (uint2*)(p + used);
        scale_kernel<<<gridN, BLOCK, 0, stream>>>(inv_lattices, forces, offsets, B, N, scaled, acc);
        for (int c = 0; c < C; ++c) {
            long long base = (long long)c * chunk_nom;
            if (base >= total) break;
            long long rem = total - base;
            int cp = (int)((rem < chunk_nom) ? rem : chunk_nom);
            hist_kernel<<<GP, BLOCK, 0, stream>>>(symm_map, base, cp, N, hist);
            scan_cols_kernel<<<NB, BLOCK, 0, stream>>>(hist, cap, offs, cnt);
            place_kernel<<<GP, BLOCK, 0, stream>>>(symm_map, scaled, general_ops, offs,
                                                   base, cp, N, O, cap, records, acc);
            accum_kernel<<<NB, BLOCK, 0, stream>>>(records, cnt, N, cap, acc);
        }
        output_kernel<<<gridN, BLOCK, 0, stream>>>(lattices, num_general_ops, offsets, B, N, acc, (float*)d_out);
    } else {
        // fallback: device-atomic scatter (uses d_out as scaled scratch)
        float* scaled_f = (float*)d_out;
        scale_kernel<<<gridN, BLOCK, 0, stream>>>(inv_lattices, forces, offsets, B, N, scaled_f, acc);
        long long gridS = (total + BLOCK - 1) / BLOCK;
        scatter_kernel<<<(int)gridS, BLOCK, 0, stream>>>(scaled_f, general_ops, symm_map, acc, total, O);
        output_kernel<<<gridN, BLOCK, 0, stream>>>(lattices, num_general_ops, offsets, B, N, acc, (float*)d_out);
    }
}

// Round 4
// 1742.741 us; speedup vs baseline: 1.1555x; 1.1555x over previous
//
#include <hip/hip_runtime.h>
#include <hip/hip_fp16.h>

#define BLOCK 256
#define NB 1024        // target buckets (bucket span <= 65536 for tgt16 trick)
#define TILE 1024      // max atoms per bucket (N <= NB*TILE for fast path)
#define GP 512         // grid for hist/place (keeps L2 open-line budget: GP/8*NB ~= 64K)
#define KSLICE 4       // accum slices per bucket (partial acc arrays)

// ---------------- offsets scan (tiny) ----------------
__global__ void scan_offsets_kernel(const int* __restrict__ num_atoms, int B,
                                    int* __restrict__ offsets) {
    __shared__ long long partial[1024];
    int t = threadIdx.x;
    int per = (B + 1023) / 1024;
    int base_idx = t * per;
    long long local = 0;
    for (int i = 0; i < per; ++i) {
        int idx = base_idx + i;
        if (idx < B) local += num_atoms[idx];
    }
    partial[t] = local;
    __syncthreads();
    for (int d = 1; d < 1024; d <<= 1) {
        long long v = (t >= d) ? partial[t - d] : 0;
        __syncthreads();
        partial[t] += v;
        __syncthreads();
    }
    long long run = (t == 0) ? 0 : partial[t - 1];
    for (int i = 0; i < per; ++i) {
        int idx = base_idx + i;
        if (idx < B) {
            offsets[idx] = (int)run;
            run += num_atoms[idx];
        }
    }
    if (t == 1023) offsets[B] = (int)partial[1023];
}

__device__ __forceinline__ int find_batch(const int* __restrict__ offsets, int B, int n) {
    int lo = 0, hi = B;
    while (hi - lo > 1) {
        int mid = (lo + hi) >> 1;
        if (offsets[mid] <= n) lo = mid; else hi = mid;
    }
    return lo;
}

// ---------------- scaled = inv_lat^T f ; zero K partial accs ----------------
__global__ void scale_kernel(const float* __restrict__ inv_lat,
                             const float* __restrict__ forces,
                             const int* __restrict__ offsets, int B, int N,
                             float* __restrict__ scaled, float* __restrict__ partials,
                             int K) {
    int n = blockIdx.x * blockDim.x + threadIdx.x;
    if (n >= N) return;
    int b = find_batch(offsets, B, n);
    const float* M = inv_lat + (size_t)b * 9;
    float f0 = forces[n * 3 + 0], f1 = forces[n * 3 + 1], f2 = forces[n * 3 + 2];
    float s0 = M[0] * f0 + M[3] * f1 + M[6] * f2;
    float s1 = M[1] * f0 + M[4] * f1 + M[7] * f2;
    float s2 = M[2] * f0 + M[5] * f1 + M[8] * f2;
    scaled[n * 3 + 0] = s0; scaled[n * 3 + 1] = s1; scaled[n * 3 + 2] = s2;
    for (int k = 0; k < K; ++k) {
        float* a = partials + (size_t)k * N * 3;
        a[n * 3 + 0] = 0.f; a[n * 3 + 1] = 0.f; a[n * 3 + 2] = 0.f;
    }
}

__device__ __forceinline__ int bucket_of(int tgt, int N) {
    return (int)(((unsigned long long)(unsigned)tgt * (unsigned)NB) / (unsigned)N);
}

// ---------------- pass 1: per-block bucket histogram (int4 loads) ----------------
__global__ __launch_bounds__(BLOCK) void hist_kernel(const int* __restrict__ symm_map,
                            long long chunk_base, int chunk_pairs, int N,
                            int* __restrict__ hist) {
    __shared__ int h[NB];
    int tid = threadIdx.x;
    for (int i = tid; i < NB; i += BLOCK) h[i] = 0;
    __syncthreads();
    int nblk = gridDim.x;
    int quantum = 4 * BLOCK;
    int span = (int)(((long long)chunk_pairs + (long long)nblk * quantum - 1) / ((long long)nblk * quantum)) * quantum;
    long long bs = (long long)blockIdx.x * span;
    int cnt = (int)((chunk_pairs - bs) < (long long)span ? (chunk_pairs - bs) : (long long)span);
    if (cnt > 0) {
        const int* p = symm_map + chunk_base + bs;
        int i0 = tid * 4;
        for (; i0 + 4 <= cnt; i0 += quantum) {
            int4 v = *(const int4*)(p + i0);
            atomicAdd(&h[bucket_of(v.x, N)], 1);
            atomicAdd(&h[bucket_of(v.y, N)], 1);
            atomicAdd(&h[bucket_of(v.z, N)], 1);
            atomicAdd(&h[bucket_of(v.w, N)], 1);
        }
        if (i0 < cnt) {
            for (int j = i0; j < cnt; ++j)
                atomicAdd(&h[bucket_of(p[j], N)], 1);
        }
    }
    __syncthreads();
    for (int i = tid; i < NB; i += BLOCK) hist[(size_t)blockIdx.x * NB + i] = h[i];
}

// ---------------- pass 2: per-bucket exclusive scan over GP blocks ----------------
__global__ __launch_bounds__(BLOCK) void scan_cols_kernel(const int* __restrict__ hist, int cap,
                                 int* __restrict__ offs, int* __restrict__ cnt) {
    const int K = GP / BLOCK;
    int b = blockIdx.x, tid = threadIdx.x;
    int v[K];
    int sum = 0;
    for (int k = 0; k < K; ++k) {
        v[k] = hist[(size_t)(tid * K + k) * NB + b];
        sum += v[k];
    }
    __shared__ int s[BLOCK];
    s[tid] = sum;
    __syncthreads();
    for (int d = 1; d < BLOCK; d <<= 1) {
        int x = (tid >= d) ? s[tid - d] : 0;
        __syncthreads();
        s[tid] += x;
        __syncthreads();
    }
    int run = b * cap + ((tid == 0) ? 0 : s[tid - 1]);
    for (int k = 0; k < K; ++k) {
        offs[(size_t)(tid * K + k) * NB + b] = run;
        run += v[k];
    }
    if (tid == BLOCK - 1) cnt[b] = (s[BLOCK - 1] < cap) ? s[BLOCK - 1] : cap;
}

// ---------------- pass 3: place 8B records grouped by bucket ----------------
// record = uint2 { h(v0) | h(v1)<<16 , h(v2) | (tgt&0xFFFF)<<16 }
__global__ __launch_bounds__(BLOCK) void place_kernel(const int* __restrict__ symm_map,
                             const float* __restrict__ scaled,
                             const float* __restrict__ general_ops,
                             const int* __restrict__ offs,
                             long long chunk_base, int chunk_pairs, int N, int O, int cap,
                             uint2* __restrict__ records, float* __restrict__ acc) {
    __shared__ int cur[NB];
    __shared__ float R[64 * 9];
    int tid = threadIdx.x;
    for (int i = tid; i < O * 9; i += BLOCK) {
        int o = i / 9, r = i - o * 9;
        R[i] = general_ops[o * 16 + (r / 3) * 4 + (r % 3)];
    }
    for (int i = tid; i < NB; i += BLOCK) cur[i] = offs[(size_t)blockIdx.x * NB + i];
    __syncthreads();
    int nblk = gridDim.x;
    int quantum = 4 * BLOCK;
    int span = (int)(((long long)chunk_pairs + (long long)nblk * quantum - 1) / ((long long)nblk * quantum)) * quantum;
    long long bs = (long long)blockIdx.x * span;
    int cnt = (int)((chunk_pairs - bs) < (long long)span ? (chunk_pairs - bs) : (long long)span);
    if (cnt <= 0) return;
    const int* p = symm_map + chunk_base + bs;
    unsigned tbase = (unsigned)(chunk_base + bs);
    unsigned uO = (unsigned)O;
    int i0 = tid * 4;
    unsigned t0 = tbase + (unsigned)i0;
    unsigned n = t0 / uO;
    unsigned o = t0 - n * uO;
    unsigned dq = (unsigned)quantum / uO;
    unsigned rq = (unsigned)quantum - dq * uO;
    for (; i0 + 4 <= cnt; i0 += quantum) {
        int4 tg = *(const int4*)(p + i0);
        unsigned nn = n, oo = o;
        #pragma unroll
        for (int j = 0; j < 4; ++j) {
            int tgt = (j == 0) ? tg.x : (j == 1) ? tg.y : (j == 2) ? tg.z : tg.w;
            const float* Ro = R + oo * 9;
            float s0 = scaled[nn * 3 + 0], s1 = scaled[nn * 3 + 1], s2 = scaled[nn * 3 + 2];
            float v0 = Ro[0] * s0 + Ro[1] * s1 + Ro[2] * s2;
            float v1 = Ro[3] * s0 + Ro[4] * s1 + Ro[5] * s2;
            float v2 = Ro[6] * s0 + Ro[7] * s1 + Ro[8] * s2;
            int bb = bucket_of(tgt, N);
            int pos = atomicAdd(&cur[bb], 1);
            if (pos - bb * cap < cap) {
                unsigned x = (unsigned)__half_as_ushort(__float2half_rn(v0)) |
                             ((unsigned)__half_as_ushort(__float2half_rn(v1)) << 16);
                unsigned y = (unsigned)__half_as_ushort(__float2half_rn(v2)) |
                             (((unsigned)tgt & 0xFFFFu) << 16);
                records[pos] = make_uint2(x, y);
            } else {
                atomicAdd(&acc[(size_t)tgt * 3 + 0], v0);
                atomicAdd(&acc[(size_t)tgt * 3 + 1], v1);
                atomicAdd(&acc[(size_t)tgt * 3 + 2], v2);
            }
            if (++oo == uO) { oo = 0; ++nn; }
        }
        o += rq;
        if (o >= uO) { o -= uO; n += dq + 1; } else n += dq;
    }
    if (i0 < cnt) {
        unsigned nn = n, oo = o;
        for (int j = i0; j < cnt; ++j) {
            int tgt = p[j];
            const float* Ro = R + oo * 9;
            float s0 = scaled[nn * 3 + 0], s1 = scaled[nn * 3 + 1], s2 = scaled[nn * 3 + 2];
            float v0 = Ro[0] * s0 + Ro[1] * s1 + Ro[2] * s2;
            float v1 = Ro[3] * s0 + Ro[4] * s1 + Ro[5] * s2;
            float v2 = Ro[6] * s0 + Ro[7] * s1 + Ro[8] * s2;
            int bb = bucket_of(tgt, N);
            int pos = atomicAdd(&cur[bb], 1);
            if (pos - bb * cap < cap) {
                unsigned x = (unsigned)__half_as_ushort(__float2half_rn(v0)) |
                             ((unsigned)__half_as_ushort(__float2half_rn(v1)) << 16);
                unsigned y = (unsigned)__half_as_ushort(__float2half_rn(v2)) |
                             (((unsigned)tgt & 0xFFFFu) << 16);
                records[pos] = make_uint2(x, y);
            } else {
                atomicAdd(&acc[(size_t)tgt * 3 + 0], v0);
                atomicAdd(&acc[(size_t)tgt * 3 + 1], v1);
                atomicAdd(&acc[(size_t)tgt * 3 + 2], v2);
            }
            if (++oo == uO) { oo = 0; ++nn; }
        }
    }
}

// ---------------- pass 4: per-(bucket,slice) LDS accumulation into partials ----------------
__global__ __launch_bounds__(BLOCK) void accum_kernel(const uint2* __restrict__ records,
                             const int* __restrict__ cnt, int N, int cap,
                             float* __restrict__ partials) {
    __shared__ float accL[TILE * 3];
    int b = blockIdx.x >> 2;          // KSLICE == 4
    int k = blockIdx.x & 3;
    int tid = threadIdx.x;
    int lo = (int)(((long long)b * N + NB - 1) / NB);
    int hi = (int)(((long long)(b + 1) * N + NB - 1) / NB);
    if (hi > N) hi = N;
    int span3 = (hi - lo) * 3;
    for (int i = tid; i < span3; i += BLOCK) accL[i] = 0.f;
    __syncthreads();
    int c = cnt[b];
    int per = (c + KSLICE - 1) / KSLICE;
    int s0i = k * per;
    int s1i = s0i + per; if (s1i > c) s1i = c;
    int myc = s1i - s0i; if (myc < 0) myc = 0;
    const uint2* r = records + (size_t)b * cap + s0i;
    int lo16 = lo & 0xFFFF;
    // pairwise uint4 loads when 16B-aligned (cap even, s0i parity varies)
    int i = 0;
    if ((((size_t)r) & 15) == 0) {
        int pairs = myc >> 1;
        const uint4* r4 = (const uint4*)r;
        for (int q = tid; q < pairs; q += BLOCK) {
            uint4 f = r4[q];
            {
                float v0 = __half2float(__ushort_as_half((unsigned short)(f.x & 0xFFFF)));
                float v1 = __half2float(__ushort_as_half((unsigned short)(f.x >> 16)));
                float v2 = __half2float(__ushort_as_half((unsigned short)(f.y & 0xFFFF)));
                int local = ((int)(f.y >> 16) - lo16) & 0xFFFF;
                atomicAdd(&accL[local * 3 + 0], v0);
                atomicAdd(&accL[local * 3 + 1], v1);
                atomicAdd(&accL[local * 3 + 2], v2);
            }
            {
                float v0 = __half2float(__ushort_as_half((unsigned short)(f.z & 0xFFFF)));
                float v1 = __half2float(__ushort_as_half((unsigned short)(f.z >> 16)));
                float v2 = __half2float(__ushort_as_half((unsigned short)(f.w & 0xFFFF)));
                int local = ((int)(f.w >> 16) - lo16) & 0xFFFF;
                atomicAdd(&accL[local * 3 + 0], v0);
                atomicAdd(&accL[local * 3 + 1], v1);
                atomicAdd(&accL[local * 3 + 2], v2);
            }
        }
        i = pairs * 2;
    }
    for (int j = i + tid; j < myc; j += BLOCK) {
        uint2 f = r[j];
        float v0 = __half2float(__ushort_as_half((unsigned short)(f.x & 0xFFFF)));
        float v1 = __half2float(__ushort_as_half((unsigned short)(f.x >> 16)));
        float v2 = __half2float(__ushort_as_half((unsigned short)(f.y & 0xFFFF)));
        int local = ((int)(f.y >> 16) - lo16) & 0xFFFF;
        atomicAdd(&accL[local * 3 + 0], v0);
        atomicAdd(&accL[local * 3 + 1], v1);
        atomicAdd(&accL[local * 3 + 2], v2);
    }
    __syncthreads();
    float* g = partials + (size_t)k * N * 3 + (size_t)lo * 3;
    for (int q = tid; q < span3; q += BLOCK) g[q] += accL[q];
}

// ---------------- fallback scatter (device atomics) ----------------
__global__ void scatter_kernel(const float* __restrict__ scaled,
                               const float* __restrict__ general_ops,
                               const int* __restrict__ symm_map,
                               float* __restrict__ acc,
                               long long total, int O) {
    __shared__ float rot_s[64 * 9];
    for (int i = threadIdx.x; i < O * 9; i += blockDim.x) {
        int o = i / 9, r = i - o * 9;
        rot_s[i] = general_ops[o * 16 + (r / 3) * 4 + (r % 3)];
    }
    __syncthreads();
    long long t = (long long)blockIdx.x * blockDim.x + threadIdx.x;
    if (t >= total) return;
    long long n = t / O;
    int o = (int)(t - n * O);
    float s0 = scaled[n * 3 + 0], s1 = scaled[n * 3 + 1], s2 = scaled[n * 3 + 2];
    const float* R = rot_s + o * 9;
    float v0 = R[0] * s0 + R[1] * s1 + R[2] * s2;
    float v1 = R[3] * s0 + R[4] * s1 + R[5] * s2;
    float v2 = R[6] * s0 + R[7] * s1 + R[8] * s2;
    int tgt = symm_map[t];
    atomicAdd(&acc[(size_t)tgt * 3 + 0], v0);
    atomicAdd(&acc[(size_t)tgt * 3 + 1], v1);
    atomicAdd(&acc[(size_t)tgt * 3 + 2], v2);
}

// ---------------- out = lat^T (sum_k partial_k / count) ----------------
__global__ void output_kernel(const float* __restrict__ lat,
                              const int* __restrict__ num_general_ops,
                              const int* __restrict__ offsets, int B, int N,
                              const float* __restrict__ partials, int K,
                              float* __restrict__ out) {
    int n = blockIdx.x * blockDim.x + threadIdx.x;
    if (n >= N) return;
    int b = find_batch(offsets, B, n);
    float inv_cnt = 1.0f / (float)num_general_ops[b];
    float a0 = 0.f, a1 = 0.f, a2 = 0.f;
    for (int k = 0; k < K; ++k) {
        const float* a = partials + (size_t)k * N * 3;
        a0 += a[n * 3 + 0]; a1 += a[n * 3 + 1]; a2 += a[n * 3 + 2];
    }
    a0 *= inv_cnt; a1 *= inv_cnt; a2 *= inv_cnt;
    const float* M = lat + (size_t)b * 9;
    out[n * 3 + 0] = M[0] * a0 + M[3] * a1 + M[6] * a2;
    out[n * 3 + 1] = M[1] * a0 + M[4] * a1 + M[7] * a2;
    out[n * 3 + 2] = M[2] * a0 + M[5] * a1 + M[8] * a2;
}

static inline size_t align16(size_t x) { return (x + 15) & ~(size_t)15; }

extern "C" void kernel_launch(void* const* d_in, const int* in_sizes, int n_in,
                              void* d_out, int out_size, void* d_ws, size_t ws_size,
                              hipStream_t stream) {
    const float* lattices        = (const float*)d_in[0];
    const float* inv_lattices    = (const float*)d_in[1];
    const float* forces          = (const float*)d_in[2];
    const int*   num_atoms       = (const int*)d_in[3];
    const float* general_ops     = (const float*)d_in[4];
    const int*   symm_map        = (const int*)d_in[5];
    const int*   num_general_ops = (const int*)d_in[6];

    int B = in_sizes[0] / 9;
    int N = in_sizes[2] / 3;
    int O = in_sizes[4] / 16;
    long long total = (long long)N * O;

    // ---- workspace layout ----
    char* p = (char*)d_ws;
    size_t used = 0;
    float* scaled   = (float*)(p + used); used = align16(used + (size_t)N * 3 * sizeof(float));
    float* partials = (float*)(p + used); used = align16(used + (size_t)KSLICE * N * 3 * sizeof(float));
    int* offsets    = (int*)(p + used);   used = align16(used + (size_t)(B + 1) * sizeof(int));
    int* hist       = (int*)(p + used);   used = align16(used + (size_t)GP * NB * sizeof(int));
    int* offs       = (int*)(p + used);   used = align16(used + (size_t)GP * NB * sizeof(int));
    int* cnt        = (int*)(p + used);   used = align16(used + (size_t)NB * sizeof(int));
    size_t remaining = (ws_size > used) ? ws_size - used : 0;

    // choose chunk count C so 8B records fit; cap = mean + 25% + 512 slack, even
    const long long quantum = 4 * BLOCK;
    int C = -1, cap = 0;
    long long chunk_nom = 0;
    for (int c = 1; c <= 64; ++c) {
        long long cp = (total + c - 1) / c;
        cp = (cp + quantum - 1) / quantum * quantum;
        long long mean = (cp + NB - 1) / NB;
        long long capc = mean + mean / 4 + 512;
        capc = (capc + 1) & ~1LL;  // even, for uint4 alignment
        if ((size_t)NB * capc * sizeof(uint2) <= remaining) { C = c; cap = (int)capc; chunk_nom = cp; break; }
    }
    bool fast = (C > 0) && ((long long)N <= (long long)NB * TILE) && (O <= 64) && (total < (1LL << 31));

    int gridN = (N + BLOCK - 1) / BLOCK;
    scan_offsets_kernel<<<1, 1024, 0, stream>>>(num_atoms, B, offsets);

    if (fast) {
        uint2* records = (uint2*)(p + used);
        scale_kernel<<<gridN, BLOCK, 0, stream>>>(inv_lattices, forces, offsets, B, N, scaled, partials, KSLICE);
        for (int c = 0; c < C; ++c) {
            long long base = (long long)c * chunk_nom;
            if (base >= total) break;
            long long rem = total - base;
            int cp = (int)((rem < chunk_nom) ? rem : chunk_nom);
            hist_kernel<<<GP, BLOCK, 0, stream>>>(symm_map, base, cp, N, hist);
            scan_cols_kernel<<<NB, BLOCK, 0, stream>>>(hist, cap, offs, cnt);
            place_kernel<<<GP, BLOCK, 0, stream>>>(symm_map, scaled, general_ops, offs,
                                                   base, cp, N, O, cap, records, partials);
            accum_kernel<<<NB * KSLICE, BLOCK, 0, stream>>>(records, cnt, N, cap, partials);
        }
        output_kernel<<<gridN, BLOCK, 0, stream>>>(lattices, num_general_ops, offsets, B, N, partials, KSLICE, (float*)d_out);
    } else {
        // fallback: device-atomic scatter into partials[0]
        scale_kernel<<<gridN, BLOCK, 0, stream>>>(inv_lattices, forces, offsets, B, N, scaled, partials, 1);
        long long gridS = (total + BLOCK - 1) / BLOCK;
        scatter_kernel<<<(int)gridS, BLOCK, 0, stream>>>(scaled, general_ops, symm_map, partials, total, O);
        output_kernel<<<gridN, BLOCK, 0, stream>>>(lattices, num_general_ops, offsets, B, N, partials, 1, (float*)d_out);
    }
}